// Round 1
// baseline (1079.862 us; speedup 1.0000x reference)
//
#include <hip/hip_runtime.h>
#include <hip/hip_bf16.h>

#define BATCH 16
#define LSEQ  2048
#define DDIM  128
#define EPSV  1e-12f

// Monotone float<->uint encoding so atomicMax(uint) implements float max.
__device__ __forceinline__ unsigned enc_f(float f) {
    unsigned u = __float_as_uint(f);
    return (u & 0x80000000u) ? ~u : (u | 0x80000000u);
}
__device__ __forceinline__ float dec_f(unsigned u) {
    return (u & 0x80000000u) ? __uint_as_float(u & 0x7FFFFFFFu)
                             : __uint_as_float(~u);
}

// ---------------------------------------------------------------------------
// K1: attn[b,i,j] = q[b,i,:].k[b,j,:]   (64x64 tile/block, K-chunk 32)
// Also reduces per-tile row max (over j) and col max (over i) into global
// encoded-uint arrays via atomics.  attn is written into the gated region.
// ---------------------------------------------------------------------------
__global__ __launch_bounds__(256) void k1_qk_gemm(
    const float* __restrict__ q, const float* __restrict__ kmat,
    float* __restrict__ attn, unsigned* __restrict__ rmax,
    unsigned* __restrict__ cmax)
{
    const int b  = blockIdx.z;
    const int it = blockIdx.y * 64;
    const int jt = blockIdx.x * 64;
    const float* qb = q    + ((size_t)b * LSEQ + it) * DDIM;
    const float* kb = kmat + ((size_t)b * LSEQ + jt) * DDIM;

    // LDS stored transposed [k][row], pad 64->68 so float4 reads stay aligned
    __shared__ float As[32][68];
    __shared__ float Bs[32][68];
    __shared__ unsigned redR[64];
    __shared__ unsigned redC[64];

    const int tid = threadIdx.x;
    const int r0 = (tid >> 4) << 2;   // 0..60 : output rows (i)
    const int c0 = (tid & 15) << 2;   // 0..60 : output cols (j)
    const int lr = tid >> 3;          // loader row 0..31
    const int lc = (tid & 7) << 2;    // loader k-col 0,4,..,28

    float acc[4][4];
#pragma unroll
    for (int u = 0; u < 4; ++u)
#pragma unroll
        for (int v = 0; v < 4; ++v) acc[u][v] = 0.f;

    // software pipeline: prefetch chunk 0
    float4 pa[2], pb[2];
#pragma unroll
    for (int p = 0; p < 2; ++p) {
        pa[p] = *(const float4*)(qb + (size_t)(lr + p * 32) * DDIM + lc);
        pb[p] = *(const float4*)(kb + (size_t)(lr + p * 32) * DDIM + lc);
    }

    for (int k0 = 0; k0 < DDIM; k0 += 32) {
#pragma unroll
        for (int p = 0; p < 2; ++p) {
            int row = lr + p * 32;
            As[lc + 0][row] = pa[p].x; As[lc + 1][row] = pa[p].y;
            As[lc + 2][row] = pa[p].z; As[lc + 3][row] = pa[p].w;
            Bs[lc + 0][row] = pb[p].x; Bs[lc + 1][row] = pb[p].y;
            Bs[lc + 2][row] = pb[p].z; Bs[lc + 3][row] = pb[p].w;
        }
        if (k0 + 32 < DDIM) {
#pragma unroll
            for (int p = 0; p < 2; ++p) {
                pa[p] = *(const float4*)(qb + (size_t)(lr + p * 32) * DDIM + k0 + 32 + lc);
                pb[p] = *(const float4*)(kb + (size_t)(lr + p * 32) * DDIM + k0 + 32 + lc);
            }
        }
        __syncthreads();
#pragma unroll
        for (int kk = 0; kk < 32; ++kk) {
            float4 av = *(const float4*)&As[kk][r0];
            float4 bv = *(const float4*)&Bs[kk][c0];
            float aa[4] = {av.x, av.y, av.z, av.w};
            float bb[4] = {bv.x, bv.y, bv.z, bv.w};
#pragma unroll
            for (int u = 0; u < 4; ++u)
#pragma unroll
                for (int v = 0; v < 4; ++v)
                    acc[u][v] = fmaf(aa[u], bb[v], acc[u][v]);
        }
        __syncthreads();
    }

    // store attn tile
    float* arow = attn + (((size_t)b * LSEQ + it) * LSEQ + jt);
    float rmax_t[4], cmax_t[4];
#pragma unroll
    for (int u = 0; u < 4; ++u) {
        rmax_t[u] = fmaxf(fmaxf(acc[u][0], acc[u][1]), fmaxf(acc[u][2], acc[u][3]));
        *(float4*)(arow + (size_t)(r0 + u) * LSEQ + c0) =
            make_float4(acc[u][0], acc[u][1], acc[u][2], acc[u][3]);
    }
#pragma unroll
    for (int v = 0; v < 4; ++v)
        cmax_t[v] = fmaxf(fmaxf(acc[0][v], acc[1][v]), fmaxf(acc[2][v], acc[3][v]));

    if (tid < 64) { redR[tid] = 0u; redC[tid] = 0u; }
    __syncthreads();
#pragma unroll
    for (int u = 0; u < 4; ++u) atomicMax(&redR[r0 + u], enc_f(rmax_t[u]));
#pragma unroll
    for (int v = 0; v < 4; ++v) atomicMax(&redC[c0 + v], enc_f(cmax_t[v]));
    __syncthreads();
    if (tid < 64) {
        atomicMax(&rmax[b * LSEQ + it + tid], redR[tid]);
        atomicMax(&cmax[b * LSEQ + jt + tid], redC[tid]);
    }
}

// ---------------------------------------------------------------------------
// K2: row sums (over j) and col sums (over i) of exp(x - m)*mask.
// Block = 256 threads = 4 waves; block covers 32 rows x full 2048 cols.
// Each wave handles 8 rows; col partials kept in registers, one atomicAdd
// per (col, wave) at the end.  Row sums: wave shuffle reduction.
// ---------------------------------------------------------------------------
__global__ __launch_bounds__(256) void k2_sums(
    const float* __restrict__ attn, const float* __restrict__ mask,
    const unsigned* __restrict__ rmax, const unsigned* __restrict__ cmax,
    float* __restrict__ rsum, float* __restrict__ csum)
{
    const int b    = blockIdx.y;
    const int it0  = blockIdx.x * 32;
    const int wave = threadIdx.x >> 6;
    const int lane = threadIdx.x & 63;

    // preload col maxes for this lane's 32 j positions
    float mc[8][4];
#pragma unroll
    for (int t = 0; t < 8; ++t) {
        uint4 m4 = *(const uint4*)(cmax + b * LSEQ + t * 256 + lane * 4);
        mc[t][0] = dec_f(m4.x); mc[t][1] = dec_f(m4.y);
        mc[t][2] = dec_f(m4.z); mc[t][3] = dec_f(m4.w);
    }
    float colacc[8][4];
#pragma unroll
    for (int t = 0; t < 8; ++t)
#pragma unroll
        for (int u = 0; u < 4; ++u) colacc[t][u] = 0.f;

    for (int rr = 0; rr < 8; ++rr) {
        const int i = it0 + wave * 8 + rr;
        const float mr = dec_f(rmax[b * LSEQ + i]);
        const float* arow = attn + ((size_t)b * LSEQ + i) * LSEQ;
        const float* mrow = mask + ((size_t)b * LSEQ + i) * LSEQ;
        float rs = 0.f;
#pragma unroll
        for (int t = 0; t < 8; ++t) {
            float4 x  = *(const float4*)(arow + t * 256 + lane * 4);
            float4 mm = *(const float4*)(mrow + t * 256 + lane * 4);
            rs += __expf(x.x - mr) * mm.x;  colacc[t][0] += __expf(x.x - mc[t][0]) * mm.x;
            rs += __expf(x.y - mr) * mm.y;  colacc[t][1] += __expf(x.y - mc[t][1]) * mm.y;
            rs += __expf(x.z - mr) * mm.z;  colacc[t][2] += __expf(x.z - mc[t][2]) * mm.z;
            rs += __expf(x.w - mr) * mm.w;  colacc[t][3] += __expf(x.w - mc[t][3]) * mm.w;
        }
#pragma unroll
        for (int off = 32; off > 0; off >>= 1) rs += __shfl_xor(rs, off, 64);
        if (lane == 0) rsum[b * LSEQ + i] = rs;
    }
#pragma unroll
    for (int t = 0; t < 8; ++t)
#pragma unroll
        for (int u = 0; u < 4; ++u)
            atomicAdd(&csum[b * LSEQ + t * 256 + lane * 4 + u], colacc[t][u]);
}

// ---------------------------------------------------------------------------
// K3: gated = mask*exp(2x - m_row - m_col)*inv_sr*inv_sc  (overwrites attn
// in place), fused with out = gated @ v.  Block: 64 rows x all j, out tile
// 64x128 accumulated in registers (thread = 4 rows x 8 cols).
// attn/mask global loads prefetched one chunk ahead (hidden under FMA).
// ---------------------------------------------------------------------------
__global__ __launch_bounds__(256) void k3_gated_out(
    const float* __restrict__ mask, const float* __restrict__ v,
    const unsigned* __restrict__ rmax, const unsigned* __restrict__ cmax,
    const float* __restrict__ rsum, const float* __restrict__ csum,
    float* __restrict__ gated, float* __restrict__ outp)
{
    const int b   = blockIdx.y;
    const int it0 = blockIdx.x * 64;

    __shared__ float Gs[32][68];     // gated chunk, transposed [j][i], padded
    __shared__ float Vs[32][128];    // v chunk [j][dv]
    __shared__ float RowM[64], RowIS[64];
    __shared__ float ColM[32], ColIS[32];

    const int tid = threadIdx.x;
    if (tid < 64) {
        const int i = it0 + tid;
        RowM[tid]  = dec_f(rmax[b * LSEQ + i]);
        RowIS[tid] = 1.f / (rsum[b * LSEQ + i] + EPSV);
    }

    const int r0  = (tid >> 4) << 2;  // out rows
    const int c0  = (tid & 15) << 2;  // out cols (and +64)
    const int gr  = tid >> 3;         // g row 0..31 (+32)
    const int gc4 = (tid & 7) << 2;   // g col-in-chunk 0,4,..,28
    const int vr  = tid >> 5;         // v loader row 0..7 (+8p)
    const int vc  = (tid & 31) << 2;  // v loader col

    float acc[4][8];
#pragma unroll
    for (int u = 0; u < 4; ++u)
#pragma unroll
        for (int w = 0; w < 8; ++w) acc[u][w] = 0.f;

    const float* mb = mask + ((size_t)b * LSEQ + it0) * LSEQ;
    float*       gb = gated + ((size_t)b * LSEQ + it0) * LSEQ;
    const float* vb = v + (size_t)b * LSEQ * DDIM;

    // prefetch chunk 0 attn+mask
    float4 xpre[2], mpre[2];
#pragma unroll
    for (int p = 0; p < 2; ++p) {
        const int row = gr + p * 32;
        xpre[p] = *(const float4*)(gb + (size_t)row * LSEQ + gc4);
        mpre[p] = *(const float4*)(mb + (size_t)row * LSEQ + gc4);
    }

    for (int j0 = 0; j0 < LSEQ; j0 += 32) {
        __syncthreads();   // previous chunk's Gs/Vs fully consumed
        if (tid < 32) {
            ColM[tid]  = dec_f(cmax[b * LSEQ + j0 + tid]);
            ColIS[tid] = 1.f / (csum[b * LSEQ + j0 + tid] + EPSV);
        }
#pragma unroll
        for (int p = 0; p < 4; ++p) {
            const int row = vr + p * 8;
            *(float4*)&Vs[row][vc] = *(const float4*)(vb + (size_t)(j0 + row) * DDIM + vc);
        }
        __syncthreads();   // ColM/ColIS (and RowM first iter) visible

        float4 xc[2] = {xpre[0], xpre[1]};
        float4 mk[2] = {mpre[0], mpre[1]};
        if (j0 + 32 < LSEQ) {
#pragma unroll
            for (int p = 0; p < 2; ++p) {
                const int row = gr + p * 32;
                xpre[p] = *(const float4*)(gb + (size_t)row * LSEQ + j0 + 32 + gc4);
                mpre[p] = *(const float4*)(mb + (size_t)row * LSEQ + j0 + 32 + gc4);
            }
        }
#pragma unroll
        for (int p = 0; p < 2; ++p) {
            const int row = gr + p * 32;
            const float mrw = RowM[row], isr = RowIS[row];
            float g0 = mk[p].x * __expf(2.f * xc[p].x - mrw - ColM[gc4 + 0]) * isr * ColIS[gc4 + 0];
            float g1 = mk[p].y * __expf(2.f * xc[p].y - mrw - ColM[gc4 + 1]) * isr * ColIS[gc4 + 1];
            float g2 = mk[p].z * __expf(2.f * xc[p].z - mrw - ColM[gc4 + 2]) * isr * ColIS[gc4 + 2];
            float g3 = mk[p].w * __expf(2.f * xc[p].w - mrw - ColM[gc4 + 3]) * isr * ColIS[gc4 + 3];
            *(float4*)(gb + (size_t)row * LSEQ + j0 + gc4) = make_float4(g0, g1, g2, g3);
            Gs[gc4 + 0][row] = g0; Gs[gc4 + 1][row] = g1;
            Gs[gc4 + 2][row] = g2; Gs[gc4 + 3][row] = g3;
        }
        __syncthreads();   // Gs ready
#pragma unroll
        for (int kk = 0; kk < 32; ++kk) {
            float4 a4 = *(const float4*)&Gs[kk][r0];
            float4 b0 = *(const float4*)&Vs[kk][c0];
            float4 b1 = *(const float4*)&Vs[kk][c0 + 64];
            float av[4] = {a4.x, a4.y, a4.z, a4.w};
            float bv[8] = {b0.x, b0.y, b0.z, b0.w, b1.x, b1.y, b1.z, b1.w};
#pragma unroll
            for (int u = 0; u < 4; ++u)
#pragma unroll
                for (int w = 0; w < 8; ++w)
                    acc[u][w] = fmaf(av[u], bv[w], acc[u][w]);
        }
    }

    float* ob = outp + ((size_t)b * LSEQ + it0) * DDIM;
#pragma unroll
    for (int u = 0; u < 4; ++u) {
        *(float4*)(ob + (size_t)(r0 + u) * DDIM + c0) =
            make_float4(acc[u][0], acc[u][1], acc[u][2], acc[u][3]);
        *(float4*)(ob + (size_t)(r0 + u) * DDIM + c0 + 64) =
            make_float4(acc[u][4], acc[u][5], acc[u][6], acc[u][7]);
    }
}

// ---------------------------------------------------------------------------
extern "C" void kernel_launch(void* const* d_in, const int* in_sizes, int n_in,
                              void* d_out, int out_size, void* d_ws, size_t ws_size,
                              hipStream_t stream)
{
    (void)in_sizes; (void)n_in; (void)out_size; (void)ws_size;
    const float* q    = (const float*)d_in[0];
    const float* k    = (const float*)d_in[1];
    const float* v    = (const float*)d_in[2];
    const float* mask = (const float*)d_in[3];

    float* outp  = (float*)d_out;                                   // B*L*D
    float* gated = (float*)d_out + (size_t)BATCH * LSEQ * DDIM;     // B*L*L (attn staged here)

    unsigned* rmax = (unsigned*)d_ws;
    unsigned* cmax = rmax + BATCH * LSEQ;
    float*    rsum = (float*)(cmax + BATCH * LSEQ);
    float*    csum = rsum + BATCH * LSEQ;

    hipMemsetAsync(d_ws, 0, sizeof(float) * 4 * BATCH * LSEQ, stream);

    dim3 g1(LSEQ / 64, LSEQ / 64, BATCH);
    k1_qk_gemm<<<g1, dim3(256), 0, stream>>>(q, k, gated, rmax, cmax);

    dim3 g2(LSEQ / 32, BATCH);
    k2_sums<<<g2, dim3(256), 0, stream>>>(gated, mask, rmax, cmax, rsum, csum);

    dim3 g3(LSEQ / 64, BATCH);
    k3_gated_out<<<g3, dim3(256), 0, stream>>>(mask, v, rmax, cmax, rsum, csum, gated, outp);
}

// Round 2
// 919.076 us; speedup vs baseline: 1.1749x; 1.1749x over previous
//
#include <hip/hip_runtime.h>

#define BATCH 16
#define LSEQ  2048
#define DDIM  128
#define EPSV  1e-12f
#define NTILE (LSEQ / 64)          // 32 tiles per dim
#define NROWS (BATCH * LSEQ)       // 32768

// ---------------------------------------------------------------------------
// K1: attn[b,i,j] = q[b,i,:].k[b,j,:]   (64x64 tile/block, K-chunk 32)
// Fused per-tile softmax stats: tile row/col max (unmasked) and tile
// row/col partial sums of exp(x - m_tile)*mask.  No global atomics.
// ---------------------------------------------------------------------------
__global__ __launch_bounds__(256) void k1_qk_stats(
    const float* __restrict__ q, const float* __restrict__ kmat,
    const float* __restrict__ mask, float* __restrict__ attn,
    float* __restrict__ rowMt, float* __restrict__ rowSt,
    float* __restrict__ colMt, float* __restrict__ colSt)
{
    const int b  = blockIdx.z;
    const int it = blockIdx.y * 64;
    const int jt = blockIdx.x * 64;
    const float* qb = q    + ((size_t)b * LSEQ + it) * DDIM;
    const float* kb = kmat + ((size_t)b * LSEQ + jt) * DDIM;

    __shared__ float As[32][68];
    __shared__ float Bs[32][68];
    __shared__ float rowMtile[64], rowStile[64];
    __shared__ float colMtile[64];
    __shared__ float colbufM[4][64], colbufS[4][64];

    const int tid = threadIdx.x;
    const int r0 = (tid >> 4) << 2;   // output rows (i), 0..60
    const int c0 = (tid & 15) << 2;   // output cols (j), 0..60
    const int lr = tid >> 3;          // loader row 0..31
    const int lc = (tid & 7) << 2;    // loader k-col

    float acc[4][4];
#pragma unroll
    for (int u = 0; u < 4; ++u)
#pragma unroll
        for (int v = 0; v < 4; ++v) acc[u][v] = 0.f;

    float4 pa[2], pb[2];
#pragma unroll
    for (int p = 0; p < 2; ++p) {
        pa[p] = *(const float4*)(qb + (size_t)(lr + p * 32) * DDIM + lc);
        pb[p] = *(const float4*)(kb + (size_t)(lr + p * 32) * DDIM + lc);
    }

    for (int k0 = 0; k0 < DDIM; k0 += 32) {
#pragma unroll
        for (int p = 0; p < 2; ++p) {
            int row = lr + p * 32;
            As[lc + 0][row] = pa[p].x; As[lc + 1][row] = pa[p].y;
            As[lc + 2][row] = pa[p].z; As[lc + 3][row] = pa[p].w;
            Bs[lc + 0][row] = pb[p].x; Bs[lc + 1][row] = pb[p].y;
            Bs[lc + 2][row] = pb[p].z; Bs[lc + 3][row] = pb[p].w;
        }
        if (k0 + 32 < DDIM) {
#pragma unroll
            for (int p = 0; p < 2; ++p) {
                pa[p] = *(const float4*)(qb + (size_t)(lr + p * 32) * DDIM + k0 + 32 + lc);
                pb[p] = *(const float4*)(kb + (size_t)(lr + p * 32) * DDIM + k0 + 32 + lc);
            }
        }
        __syncthreads();
#pragma unroll
        for (int kk = 0; kk < 32; ++kk) {
            float4 av = *(const float4*)&As[kk][r0];
            float4 bv = *(const float4*)&Bs[kk][c0];
            float aa[4] = {av.x, av.y, av.z, av.w};
            float bb[4] = {bv.x, bv.y, bv.z, bv.w};
#pragma unroll
            for (int u = 0; u < 4; ++u)
#pragma unroll
                for (int v = 0; v < 4; ++v)
                    acc[u][v] = fmaf(aa[u], bb[v], acc[u][v]);
        }
        __syncthreads();
    }

    // issue mask tile loads early (needed in phase B)
    const float* mb = mask + (((size_t)b * LSEQ + it) * LSEQ + jt);
    float4 mtile[4];
#pragma unroll
    for (int u = 0; u < 4; ++u)
        mtile[u] = *(const float4*)(mb + (size_t)(r0 + u) * LSEQ + c0);

    // store attn tile
    float* arow = attn + (((size_t)b * LSEQ + it) * LSEQ + jt);
#pragma unroll
    for (int u = 0; u < 4; ++u)
        *(float4*)(arow + (size_t)(r0 + u) * LSEQ + c0) =
            make_float4(acc[u][0], acc[u][1], acc[u][2], acc[u][3]);

    // ---- phase A: tile row/col maxes (unmasked) ----
#pragma unroll
    for (int u = 0; u < 4; ++u) {
        float m = fmaxf(fmaxf(acc[u][0], acc[u][1]), fmaxf(acc[u][2], acc[u][3]));
        m = fmaxf(m, __shfl_xor(m, 1, 64));
        m = fmaxf(m, __shfl_xor(m, 2, 64));
        m = fmaxf(m, __shfl_xor(m, 4, 64));
        m = fmaxf(m, __shfl_xor(m, 8, 64));
        if ((tid & 15) == 0) rowMtile[r0 + u] = m;
    }
#pragma unroll
    for (int v = 0; v < 4; ++v) {
        float m = fmaxf(fmaxf(acc[0][v], acc[1][v]), fmaxf(acc[2][v], acc[3][v]));
        m = fmaxf(m, __shfl_xor(m, 16, 64));
        m = fmaxf(m, __shfl_xor(m, 32, 64));
        if ((tid & 63) < 16) colbufM[tid >> 6][c0 + v] = m;
    }
    __syncthreads();
    if (tid < 64)
        colMtile[tid] = fmaxf(fmaxf(colbufM[0][tid], colbufM[1][tid]),
                              fmaxf(colbufM[2][tid], colbufM[3][tid]));
    __syncthreads();

    // ---- phase B: tile partial sums of exp(x - m_tile)*mask ----
    float cs[4] = {0.f, 0.f, 0.f, 0.f};
    float mc[4] = {colMtile[c0], colMtile[c0 + 1], colMtile[c0 + 2], colMtile[c0 + 3]};
#pragma unroll
    for (int u = 0; u < 4; ++u) {
        const float mr = rowMtile[r0 + u];
        const float mm[4] = {mtile[u].x, mtile[u].y, mtile[u].z, mtile[u].w};
        float rs = 0.f;
#pragma unroll
        for (int v = 0; v < 4; ++v) {
            const float x = acc[u][v];
            rs    += __expf(x - mr)    * mm[v];
            cs[v] += __expf(x - mc[v]) * mm[v];
        }
        rs += __shfl_xor(rs, 1, 64);
        rs += __shfl_xor(rs, 2, 64);
        rs += __shfl_xor(rs, 4, 64);
        rs += __shfl_xor(rs, 8, 64);
        if ((tid & 15) == 0) rowStile[r0 + u] = rs;
    }
#pragma unroll
    for (int v = 0; v < 4; ++v) {
        float s = cs[v];
        s += __shfl_xor(s, 16, 64);
        s += __shfl_xor(s, 32, 64);
        if ((tid & 63) < 16) colbufS[tid >> 6][c0 + v] = s;
    }
    __syncthreads();

    if (tid < 64) {
        const float colS = colbufS[0][tid] + colbufS[1][tid] +
                           colbufS[2][tid] + colbufS[3][tid];
        const size_t rIdx = (size_t)blockIdx.x * NROWS + b * LSEQ + it + tid;
        const size_t cIdx = (size_t)blockIdx.y * NROWS + b * LSEQ + jt + tid;
        rowMt[rIdx] = rowMtile[tid];
        rowSt[rIdx] = rowStile[tid];
        colMt[cIdx] = colMtile[tid];
        colSt[cIdx] = colS;
    }
}

// ---------------------------------------------------------------------------
// K2: combine per-tile stats -> global max & sum per row / col.
// ---------------------------------------------------------------------------
__global__ __launch_bounds__(256) void k2_combine(
    const float* __restrict__ rowMt, const float* __restrict__ rowSt,
    const float* __restrict__ colMt, const float* __restrict__ colSt,
    float* __restrict__ rmaxf, float* __restrict__ rsumf,
    float* __restrict__ cmaxf, float* __restrict__ csumf)
{
    const int id = blockIdx.x * 256 + threadIdx.x;   // [0, 2*NROWS)
    const bool isRow = (id < NROWS);
    const int off = isRow ? id : id - NROWS;
    const float* Mt = isRow ? rowMt : colMt;
    const float* St = isRow ? rowSt : colSt;

    float m = -INFINITY;
#pragma unroll
    for (int t = 0; t < NTILE; ++t) m = fmaxf(m, Mt[(size_t)t * NROWS + off]);
    float s = 0.f;
#pragma unroll
    for (int t = 0; t < NTILE; ++t)
        s += St[(size_t)t * NROWS + off] * __expf(Mt[(size_t)t * NROWS + off] - m);

    if (isRow) { rmaxf[off] = m; rsumf[off] = s; }
    else       { cmaxf[off] = m; csumf[off] = s; }
}

// ---------------------------------------------------------------------------
// K3: gated = mask*exp(2x - m_row - m_col)/( (sr+eps)(sc+eps) ), in place over
// attn, fused with out = gated @ v.  32 rows/block (1024 blocks -> occupancy).
// Thread microtile 4x4 over the 32x128 out tile.
// ---------------------------------------------------------------------------
__global__ __launch_bounds__(256) void k3_gated_out(
    const float* __restrict__ mask, const float* __restrict__ v,
    const float* __restrict__ rmaxf, const float* __restrict__ cmaxf,
    const float* __restrict__ rsumf, const float* __restrict__ csumf,
    float* __restrict__ gated, float* __restrict__ outp)
{
    const int b   = blockIdx.y;
    const int it0 = blockIdx.x * 32;

    __shared__ float Gs[32][36];     // gated chunk, transposed [j][i]
    __shared__ float Vs[32][128];    // v chunk [j][dv]
    __shared__ float RowM[32], RowIS[32];
    __shared__ float ColM[32], ColIS[32];

    const int tid = threadIdx.x;
    if (tid < 32) {
        RowM[tid]  = rmaxf[b * LSEQ + it0 + tid];
        RowIS[tid] = 1.f / (rsumf[b * LSEQ + it0 + tid] + EPSV);
    }

    const int r0  = (tid >> 5) << 2;  // out rows 0..28
    const int c0  = (tid & 31) << 2;  // out cols 0..124
    const int gr  = tid >> 3;         // gated row 0..31
    const int gc4 = (tid & 7) << 2;   // gated col-in-chunk
    const int vr  = tid >> 5;         // v loader row 0..7 (+8p)
    const int vc  = (tid & 31) << 2;  // v loader col

    float acc[4][4];
#pragma unroll
    for (int u = 0; u < 4; ++u)
#pragma unroll
        for (int w = 0; w < 4; ++w) acc[u][w] = 0.f;

    const float* mb = mask  + ((size_t)b * LSEQ + it0) * LSEQ;
    float*       gb = gated + ((size_t)b * LSEQ + it0) * LSEQ;
    const float* vb = v + (size_t)b * LSEQ * DDIM;

    float4 xpre = *(const float4*)(gb + (size_t)gr * LSEQ + gc4);
    float4 mpre = *(const float4*)(mb + (size_t)gr * LSEQ + gc4);

    for (int j0 = 0; j0 < LSEQ; j0 += 32) {
        __syncthreads();   // previous chunk fully consumed
        if (tid < 32) {
            ColM[tid]  = cmaxf[b * LSEQ + j0 + tid];
            ColIS[tid] = 1.f / (csumf[b * LSEQ + j0 + tid] + EPSV);
        }
#pragma unroll
        for (int p = 0; p < 4; ++p) {
            const int row = vr + p * 8;
            *(float4*)&Vs[row][vc] = *(const float4*)(vb + (size_t)(j0 + row) * DDIM + vc);
        }
        __syncthreads();   // ColM/ColIS + Vs visible

        float4 xc = xpre, mk = mpre;
        if (j0 + 32 < LSEQ) {
            xpre = *(const float4*)(gb + (size_t)gr * LSEQ + j0 + 32 + gc4);
            mpre = *(const float4*)(mb + (size_t)gr * LSEQ + j0 + 32 + gc4);
        }
        {
            const float mrw = RowM[gr], isr = RowIS[gr];
            float g0 = mk.x * __expf(2.f * xc.x - mrw - ColM[gc4 + 0]) * isr * ColIS[gc4 + 0];
            float g1 = mk.y * __expf(2.f * xc.y - mrw - ColM[gc4 + 1]) * isr * ColIS[gc4 + 1];
            float g2 = mk.z * __expf(2.f * xc.z - mrw - ColM[gc4 + 2]) * isr * ColIS[gc4 + 2];
            float g3 = mk.w * __expf(2.f * xc.w - mrw - ColM[gc4 + 3]) * isr * ColIS[gc4 + 3];
            *(float4*)(gb + (size_t)gr * LSEQ + j0 + gc4) = make_float4(g0, g1, g2, g3);
            Gs[gc4 + 0][gr] = g0; Gs[gc4 + 1][gr] = g1;
            Gs[gc4 + 2][gr] = g2; Gs[gc4 + 3][gr] = g3;
        }
        __syncthreads();   // Gs ready
#pragma unroll
        for (int kk = 0; kk < 32; ++kk) {
            float4 a4 = *(const float4*)&Gs[kk][r0];
            float4 b4 = *(const float4*)&Vs[kk][c0];
            float av[4] = {a4.x, a4.y, a4.z, a4.w};
            float bv[4] = {b4.x, b4.y, b4.z, b4.w};
#pragma unroll
            for (int u = 0; u < 4; ++u)
#pragma unroll
                for (int w = 0; w < 4; ++w)
                    acc[u][w] = fmaf(av[u], bv[w], acc[u][w]);
        }
    }

    float* ob = outp + ((size_t)b * LSEQ + it0) * DDIM;
#pragma unroll
    for (int u = 0; u < 4; ++u)
        *(float4*)(ob + (size_t)(r0 + u) * DDIM + c0) =
            make_float4(acc[u][0], acc[u][1], acc[u][2], acc[u][3]);
}

// ---------------------------------------------------------------------------
extern "C" void kernel_launch(void* const* d_in, const int* in_sizes, int n_in,
                              void* d_out, int out_size, void* d_ws, size_t ws_size,
                              hipStream_t stream)
{
    (void)in_sizes; (void)n_in; (void)out_size; (void)ws_size;
    const float* q    = (const float*)d_in[0];
    const float* k    = (const float*)d_in[1];
    const float* v    = (const float*)d_in[2];
    const float* mask = (const float*)d_in[3];

    float* outp  = (float*)d_out;                                   // B*L*D
    float* gated = (float*)d_out + (size_t)BATCH * LSEQ * DDIM;     // B*L*L

    float* rowMt = (float*)d_ws;                 // [NTILE][NROWS]
    float* rowSt = rowMt + (size_t)NTILE * NROWS;
    float* colMt = rowSt + (size_t)NTILE * NROWS;
    float* colSt = colMt + (size_t)NTILE * NROWS;
    float* rmaxf = colSt + (size_t)NTILE * NROWS;
    float* rsumf = rmaxf + NROWS;
    float* cmaxf = rsumf + NROWS;
    float* csumf = cmaxf + NROWS;

    dim3 g1(LSEQ / 64, LSEQ / 64, BATCH);
    k1_qk_stats<<<g1, dim3(256), 0, stream>>>(q, k, mask, gated,
                                              rowMt, rowSt, colMt, colSt);

    k2_combine<<<dim3(2 * NROWS / 256), dim3(256), 0, stream>>>(
        rowMt, rowSt, colMt, colSt, rmaxf, rsumf, cmaxf, csumf);

    dim3 g3(LSEQ / 32, BATCH);
    k3_gated_out<<<g3, dim3(256), 0, stream>>>(mask, v, rmaxf, cmaxf,
                                               rsumf, csumf, gated, outp);
}